// Round 12
// baseline (109.558 us; speedup 1.0000x reference)
//
#include <hip/hip_runtime.h>

typedef __attribute__((ext_vector_type(8))) short short8;
typedef __attribute__((ext_vector_type(4))) float f32x4;
typedef __attribute__((ext_vector_type(8))) unsigned short ushort8;

__device__ __forceinline__ unsigned short f2bf(float x) {
  union { float f; unsigned u; } v; v.f = x;
  unsigned r = v.u + 0x7fffu + ((v.u >> 16) & 1u);   // round-to-nearest-even
  return (unsigned short)(r >> 16);
}

// ---------------- W[h][g] -> Wt[g][h] transpose + convert (512x512) ----------
__global__ __launch_bounds__(256) void wt_kernel(
    const float* __restrict__ W, unsigned short* __restrict__ Wt) {
  __shared__ float s[64][65];
  int g0 = blockIdx.x * 64, h0 = blockIdx.y * 64;
  int tx = threadIdx.x & 63, ty = threadIdx.x >> 6;
#pragma unroll
  for (int rr = 0; rr < 16; ++rr) {
    int h = ty * 16 + rr;
    s[h][tx] = W[(long)(h0 + h) * 512 + g0 + tx];
  }
  __syncthreads();
#pragma unroll
  for (int rr = 0; rr < 16; ++rr) {
    int g = ty * 16 + rr;
    Wt[(long)(g0 + g) * 512 + h0 + tx] = f2bf(s[tx][g]);
  }
}

// ---- Fused: gemm1 (blocks 0..511) + dec fp32->bf16 convert (blocks 512..4607)
__global__ __launch_bounds__(256) void gemm1_plus_cvtdec(
    const float* __restrict__ enc, const unsigned short* __restrict__ Wt,
    unsigned short* __restrict__ encW,
    const float* __restrict__ dec, unsigned short* __restrict__ dec_bf) {
  if (blockIdx.x >= 512) {
    int i = (blockIdx.x - 512) * 256 + threadIdx.x;
    const float4* p = (const float4*)(dec + (long)i * 8);
    float4 a = p[0], b = p[1];
    ushort8 o;
    o[0] = f2bf(a.x); o[1] = f2bf(a.y); o[2] = f2bf(a.z); o[3] = f2bf(a.w);
    o[4] = f2bf(b.x); o[5] = f2bf(b.y); o[6] = f2bf(b.z); o[7] = f2bf(b.w);
    *(ushort8*)(dec_bf + (long)i * 8) = o;
    return;
  }

  constexpr int K = 512, N = 512, BK = 32;
  __shared__ __align__(16) short As[128 * BK];
  __shared__ __align__(16) short Bs[128 * BK];

  const int g = blockIdx.x;
  const int work = (g & 7) * 64 + (g >> 3);      // bijective on [0,512)
  const int bxm = work >> 2, byn = work & 3;

  const int tid = threadIdx.x;
  const int wave = tid >> 6, lane = tid & 63;
  const int wm = wave >> 1, wn = wave & 1;
  const int r = lane & 15, q = lane >> 4;

  const float* Ab = enc + (long)bxm * 128 * K;
  const unsigned short* Bb = Wt + (long)byn * 128 * K;

  const int srow = tid >> 1, shalf = tid & 1;
  const float* arow = Ab + (long)srow * K + shalf * 16;

  f32x4 acc[4][4] = {};
  float4 av[4];
#pragma unroll
  for (int j = 0; j < 4; ++j) av[j] = ((const float4*)arow)[j];

  for (int kt = 0; kt < K; kt += BK) {
    ushort8 o0, o1;
    o0[0] = f2bf(av[0].x); o0[1] = f2bf(av[0].y); o0[2] = f2bf(av[0].z); o0[3] = f2bf(av[0].w);
    o0[4] = f2bf(av[1].x); o0[5] = f2bf(av[1].y); o0[6] = f2bf(av[1].z); o0[7] = f2bf(av[1].w);
    o1[0] = f2bf(av[2].x); o1[1] = f2bf(av[2].y); o1[2] = f2bf(av[2].z); o1[3] = f2bf(av[2].w);
    o1[4] = f2bf(av[3].x); o1[5] = f2bf(av[3].y); o1[6] = f2bf(av[3].z); o1[7] = f2bf(av[3].w);
    *(ushort8*)&As[srow * BK + shalf * 16 + 0] = o0;
    *(ushort8*)&As[srow * BK + shalf * 16 + 8] = o1;

#pragma unroll
    for (int j = 0; j < 2; ++j) {
      int c = (j * 4 + wave) * 64 + lane;
      int row = c >> 2;
      int coff = (c & 3) * 8;
      __builtin_amdgcn_global_load_lds(
          (const __attribute__((address_space(1))) void*)(Bb + (long)row * K + kt + coff),
          (__attribute__((address_space(3))) void*)(Bs + (j * 4 + wave) * 512),
          16, 0, 0);
    }
    __syncthreads();

    short8 af[4], bfr[4];
#pragma unroll
    for (int m = 0; m < 4; ++m)
      af[m] = *(const short8*)&As[(wm * 64 + m * 16 + r) * BK + q * 8];
#pragma unroll
    for (int n = 0; n < 4; ++n)
      bfr[n] = *(const short8*)&Bs[(wn * 64 + n * 16 + r) * BK + q * 8];

    if (kt + BK < K) {
      const float* ap = arow + kt + BK;
#pragma unroll
      for (int j = 0; j < 4; ++j) av[j] = ((const float4*)ap)[j];
    }

#pragma unroll
    for (int m = 0; m < 4; ++m)
#pragma unroll
      for (int n = 0; n < 4; ++n)
        acc[m][n] = __builtin_amdgcn_mfma_f32_16x16x32_bf16(af[m], bfr[n], acc[m][n], 0, 0, 0);
    __syncthreads();
  }

  const long rowbase = (long)bxm * 128 + wm * 64;
  const long colbase = (long)byn * 128 + wn * 64;
#pragma unroll
  for (int m = 0; m < 4; ++m)
#pragma unroll
    for (int n = 0; n < 4; ++n)
#pragma unroll
      for (int j = 0; j < 4; ++j) {
        long row = rowbase + m * 16 + q * 4 + j;
        long col = colbase + n * 16 + r;
        encW[row * (long)N + col] = f2bf(acc[m][n][j]);
      }
}

// ---------------- GEMM2: 128x128, BK=128, T14 async reg-staging --------------
// scores[b][d][e] = sum_g dec_bf[b,d,g] * encW[b,e,g] + bias
// Same geometry/LDS-bytes/swizzle/epilogue as R11 (gemm2_bk128), ONE change:
// staging goes global->reg (16 dwordx4 issued a FULL compute-window early)
// then reg->LDS after the post-compute barrier. vmcnt(0) at write time is
// free (loads had ~1240 cyc to fly). Raw s_barrier (not __syncthreads) so
// the in-flight prefetch is NOT drained at the barrier.
#define VMCNT0 asm volatile("s_waitcnt vmcnt(0)" ::: "memory")
#define LGKM0  asm volatile("s_waitcnt lgkmcnt(0)" ::: "memory")
#define BARRIER asm volatile("s_barrier" ::: "memory")

__global__ __launch_bounds__(256, 2) void gemm2_t14(
    const unsigned short* __restrict__ A,   // dec_bf [8*2048][512]
    const unsigned short* __restrict__ Bt,  // encW   [8*2048][512]
    float* __restrict__ C, const float* __restrict__ bias) {
  __shared__ __align__(16) char As[32768];   // 128 rows x 128 k bf16
  __shared__ __align__(16) char Bs[32768];

  // grid 2048 = 8 batches x 16x16 tiles; z = blk&7 pins batch -> XCD (4MB L2)
  const int flat = blockIdx.x;
  const int z = flat & 7;
  const int work = flat >> 3;
  const int by = work & 15, bx = work >> 4;

  const int tid = threadIdx.x;
  const int w = tid >> 6, lane = tid & 63;
  const int wm = w >> 1, wn = w & 1;         // 2x2 waves, 64x64 out each
  const int base_r = lane & 15, q = lane >> 4;
  const int lconst = base_r * 64 + ((q * 16) ^ ((base_r & 8) << 2));
  const int srow = lane >> 2;
  const int scol = ((lane & 3) * 8) ^ (((lane >> 5) & 1) << 4);

  const unsigned short* Ab = A + ((long)z * 2048 + bx * 128) * 512;
  const unsigned short* Bb = Bt + ((long)z * 2048 + by * 128) * 512;

  f32x4 acc[4][4] = {};
  float4 ast[8], bst[8];                     // in-flight window (64 VGPR)

  // issue loads for window kt: chunk c = w*8+j, rowc=c>>2, kk=c&3;
  // per-lane src pre-swizzled so LDS content matches the gload_lds layout.
#define LOADW(KT)                                                             \
  _Pragma("unroll") for (int j = 0; j < 8; ++j) {                             \
    int c = w * 8 + j, rowc = c >> 2, kk = c & 3;                             \
    long off = (long)(rowc * 16 + srow) * 512 + (KT) * 128 + kk * 32 + scol;  \
    ast[j] = *(const float4*)(Ab + off);                                      \
    bst[j] = *(const float4*)(Bb + off);                                      \
  }

#define WRITEW                                                                \
  _Pragma("unroll") for (int j = 0; j < 8; ++j) {                             \
    int c = w * 8 + j;                                                        \
    *(float4*)(As + (c << 10) + lane * 16) = ast[j];                          \
    *(float4*)(Bs + (c << 10) + lane * 16) = bst[j];                          \
  }

#define COMPUTEW                                                              \
  _Pragma("unroll") for (int kk = 0; kk < 4; ++kk) {                          \
    short8 af[4], bfr[4];                                                     \
    _Pragma("unroll") for (int m = 0; m < 4; ++m)                             \
      af[m] = *(const short8*)(As + (((wm * 4 + m) * 4 + kk) << 10) + lconst);\
    _Pragma("unroll") for (int n = 0; n < 4; ++n)                             \
      bfr[n] = *(const short8*)(Bs + (((wn * 4 + n) * 4 + kk) << 10) + lconst);\
    _Pragma("unroll") for (int m = 0; m < 4; ++m)                             \
      _Pragma("unroll") for (int n = 0; n < 4; ++n)                           \
        acc[m][n] = __builtin_amdgcn_mfma_f32_16x16x32_bf16(                  \
            af[m], bfr[n], acc[m][n], 0, 0, 0);                               \
  }

  // prologue: window 0 loads -> LDS
  LOADW(0);
  VMCNT0;
  WRITEW;
  LGKM0;
  BARRIER;

#pragma unroll
  for (int kt = 0; kt < 4; ++kt) {
    if (kt < 3) LOADW(kt + 1);     // issue next window; flies under compute
    COMPUTEW;                      // 64 MFMA/wave + swizzled ds_reads
    BARRIER;                       // all waves done reading (raw: no drain)
    if (kt < 3) {
      VMCNT0;                      // loads landed during compute
      WRITEW;
      LGKM0;
    }
    BARRIER;
  }

  const float bv = bias[0];
  float* Cb = C + ((long)z * 2048 + bx * 128 + wm * 64) * 2048 + by * 128 + wn * 64;
#pragma unroll
  for (int m = 0; m < 4; ++m)
#pragma unroll
    for (int n = 0; n < 4; ++n)
#pragma unroll
      for (int j = 0; j < 4; ++j)
        Cb[(long)(m * 16 + q * 4 + j) * 2048 + n * 16 + base_r] = acc[m][n][j] + bv;
#undef LOADW
#undef WRITEW
#undef COMPUTEW
}

extern "C" void kernel_launch(void* const* d_in, const int* in_sizes, int n_in,
                              void* d_out, int out_size, void* d_ws, size_t ws_size,
                              hipStream_t stream) {
  const float* enc  = (const float*)d_in[0];  // [8,2048,512]
  const float* dec  = (const float*)d_in[1];  // [8,2048,512]
  const float* W    = (const float*)d_in[2];  // [1,512,512]
  const float* bias = (const float*)d_in[3];  // [1]
  float* out = (float*)d_out;                 // [8,2048,2048] fp32

  constexpr int Bn = 8, S = 2048, H = 512;
  constexpr long NE = (long)Bn * S * H;       // 8388608

  unsigned short* dec_bf = (unsigned short*)d_ws;        // 16.8 MB
  unsigned short* Wt     = dec_bf + NE;                  // 0.5 MB
  unsigned short* encW   = Wt + (long)H * H;             // 16.8 MB

  wt_kernel<<<dim3(8, 8), 256, 0, stream>>>(W, Wt);

  // gemm1 (512 blocks) + dec conversion (4096 blocks) in one launch
  gemm1_plus_cvtdec<<<dim3(512 + 4096, 1, 1), 256, 0, stream>>>(
      enc, Wt, encW, dec, dec_bf);

  // scores[b][d][e] = dec[b,d,:] . encW[b,e,:] + bias
  gemm2_t14<<<dim3(2048, 1, 1), 256, 0, stream>>>(dec_bf, encW, out, bias);
}

// Round 14
// 79.402 us; speedup vs baseline: 1.3798x; 1.3798x over previous
//
#include <hip/hip_runtime.h>

typedef __attribute__((ext_vector_type(8))) short short8;
typedef __attribute__((ext_vector_type(4))) float f32x4;
typedef __attribute__((ext_vector_type(8))) unsigned short ushort8;

__device__ __forceinline__ unsigned short f2bf(float x) {
  union { float f; unsigned u; } v; v.f = x;
  unsigned r = v.u + 0x7fffu + ((v.u >> 16) & 1u);   // round-to-nearest-even
  return (unsigned short)(r >> 16);
}

// ---------------- W[h][g] -> Wt[g][h] transpose + convert (512x512) ----------
__global__ __launch_bounds__(256) void wt_kernel(
    const float* __restrict__ W, unsigned short* __restrict__ Wt) {
  __shared__ float s[64][65];
  int g0 = blockIdx.x * 64, h0 = blockIdx.y * 64;
  int tx = threadIdx.x & 63, ty = threadIdx.x >> 6;
#pragma unroll
  for (int rr = 0; rr < 16; ++rr) {
    int h = ty * 16 + rr;
    s[h][tx] = W[(long)(h0 + h) * 512 + g0 + tx];
  }
  __syncthreads();
#pragma unroll
  for (int rr = 0; rr < 16; ++rr) {
    int g = ty * 16 + rr;
    Wt[(long)(g0 + g) * 512 + h0 + tx] = f2bf(s[tx][g]);
  }
}

// ---- Fused: gemm1 (blocks 0..511) + dec fp32->bf16 convert (blocks 512..4607)
__global__ __launch_bounds__(256) void gemm1_plus_cvtdec(
    const float* __restrict__ enc, const unsigned short* __restrict__ Wt,
    unsigned short* __restrict__ encW,
    const float* __restrict__ dec, unsigned short* __restrict__ dec_bf) {
  if (blockIdx.x >= 512) {
    int i = (blockIdx.x - 512) * 256 + threadIdx.x;
    const float4* p = (const float4*)(dec + (long)i * 8);
    float4 a = p[0], b = p[1];
    ushort8 o;
    o[0] = f2bf(a.x); o[1] = f2bf(a.y); o[2] = f2bf(a.z); o[3] = f2bf(a.w);
    o[4] = f2bf(b.x); o[5] = f2bf(b.y); o[6] = f2bf(b.z); o[7] = f2bf(b.w);
    *(ushort8*)(dec_bf + (long)i * 8) = o;
    return;
  }

  constexpr int K = 512, N = 512, BK = 32;
  __shared__ __align__(16) short As[128 * BK];
  __shared__ __align__(16) short Bs[128 * BK];

  const int g = blockIdx.x;
  const int work = (g & 7) * 64 + (g >> 3);      // bijective on [0,512)
  const int bxm = work >> 2, byn = work & 3;

  const int tid = threadIdx.x;
  const int wave = tid >> 6, lane = tid & 63;
  const int wm = wave >> 1, wn = wave & 1;
  const int r = lane & 15, q = lane >> 4;

  const float* Ab = enc + (long)bxm * 128 * K;
  const unsigned short* Bb = Wt + (long)byn * 128 * K;

  const int srow = tid >> 1, shalf = tid & 1;
  const float* arow = Ab + (long)srow * K + shalf * 16;

  f32x4 acc[4][4] = {};
  float4 av[4];
#pragma unroll
  for (int j = 0; j < 4; ++j) av[j] = ((const float4*)arow)[j];

  for (int kt = 0; kt < K; kt += BK) {
    ushort8 o0, o1;
    o0[0] = f2bf(av[0].x); o0[1] = f2bf(av[0].y); o0[2] = f2bf(av[0].z); o0[3] = f2bf(av[0].w);
    o0[4] = f2bf(av[1].x); o0[5] = f2bf(av[1].y); o0[6] = f2bf(av[1].z); o0[7] = f2bf(av[1].w);
    o1[0] = f2bf(av[2].x); o1[1] = f2bf(av[2].y); o1[2] = f2bf(av[2].z); o1[3] = f2bf(av[2].w);
    o1[4] = f2bf(av[3].x); o1[5] = f2bf(av[3].y); o1[6] = f2bf(av[3].z); o1[7] = f2bf(av[3].w);
    *(ushort8*)&As[srow * BK + shalf * 16 + 0] = o0;
    *(ushort8*)&As[srow * BK + shalf * 16 + 8] = o1;

#pragma unroll
    for (int j = 0; j < 2; ++j) {
      int c = (j * 4 + wave) * 64 + lane;
      int row = c >> 2;
      int coff = (c & 3) * 8;
      __builtin_amdgcn_global_load_lds(
          (const __attribute__((address_space(1))) void*)(Bb + (long)row * K + kt + coff),
          (__attribute__((address_space(3))) void*)(Bs + (j * 4 + wave) * 512),
          16, 0, 0);
    }
    __syncthreads();

    short8 af[4], bfr[4];
#pragma unroll
    for (int m = 0; m < 4; ++m)
      af[m] = *(const short8*)&As[(wm * 64 + m * 16 + r) * BK + q * 8];
#pragma unroll
    for (int n = 0; n < 4; ++n)
      bfr[n] = *(const short8*)&Bs[(wn * 64 + n * 16 + r) * BK + q * 8];

    if (kt + BK < K) {
      const float* ap = arow + kt + BK;
#pragma unroll
      for (int j = 0; j < 4; ++j) av[j] = ((const float4*)ap)[j];
    }

#pragma unroll
    for (int m = 0; m < 4; ++m)
#pragma unroll
      for (int n = 0; n < 4; ++n)
        acc[m][n] = __builtin_amdgcn_mfma_f32_16x16x32_bf16(af[m], bfr[n], acc[m][n], 0, 0, 0);
    __syncthreads();
  }

  const long rowbase = (long)bxm * 128 + wm * 64;
  const long colbase = (long)byn * 128 + wn * 64;
#pragma unroll
  for (int m = 0; m < 4; ++m)
#pragma unroll
    for (int n = 0; n < 4; ++n)
#pragma unroll
      for (int j = 0; j < 4; ++j) {
        long row = rowbase + m * 16 + q * 4 + j;
        long col = colbase + n * 16 + r;
        encW[row * (long)N + col] = f2bf(acc[m][n][j]);
      }
}

// ------- GEMM2: faithful 256^2 8-phase template (tail staging fixed) ---------
// 512 thr = 8 waves (2M x 4N), per-wave 128x64 out, acc[8][4]. BK=64.
// LDS 128KB: A dbuf 2 x (2 halves x 16KB), B same. Half-tile = 128 rows x 64 k.
// Phases = C-quadrants x 2 K-tiles; 16 MFMA/phase; af/bf register reuse;
// 1 half-tile staged/phase (2 loads/thread, own-vmcnt->barrier->read);
// vmcnt(4) at ph4 & ph8 only. TAIL FIX: stage T7.A1/T7.B1 at tail ph1/ph2,
// VMCNT(0) at tail ph4 before reading buffer 1 (R13 bug: tile 7 halves were
// never staged -> stale T5 data, absmax 40).
#define VMCNT(n) asm volatile("s_waitcnt vmcnt(" #n ")" ::: "memory")
#define LGKM0  asm volatile("s_waitcnt lgkmcnt(0)" ::: "memory")
#define BAR __builtin_amdgcn_s_barrier()

#define LA(p, h) (Lds + (p) * 32768 + (h) * 16384)
#define LB(p, h) (Lds + 65536 + (p) * 32768 + (h) * 16384)

#define STGH(GP, LBASE, T, H)                                                 \
  do {                                                                        \
    _Pragma("unroll") for (int j_ = 0; j_ < 2; ++j_) {                        \
      int c_ = w * 2 + j_;                                                    \
      __builtin_amdgcn_global_load_lds(                                       \
          (const __attribute__((address_space(1))) void*)(                    \
              (GP) + ((long)((H) * 128 + (c_ >> 1) * 16 + srow)) * 512 +      \
              (T) * 64 + (c_ & 1) * 32 + scol),                               \
          (__attribute__((address_space(3))) void*)((LBASE) + (c_ << 10)),    \
          16, 0, 0);                                                          \
    }                                                                         \
  } while (0)

#define LOADAF(p, mh)                                                         \
  _Pragma("unroll") for (int mi_ = 0; mi_ < 4; ++mi_)                         \
    _Pragma("unroll") for (int ks_ = 0; ks_ < 2; ++ks_)                       \
      af[mi_][ks_] = *(const short8*)(LA(p, wm) +                             \
          ((((mh) * 4 + mi_) * 2 + ks_) << 10) + lconst)

#define LOADBF(p, nh)                                                         \
  _Pragma("unroll") for (int n_ = 0; n_ < 2; ++n_)                            \
    _Pragma("unroll") for (int ks_ = 0; ks_ < 2; ++ks_)                       \
      bf[nh][n_][ks_] = *(const short8*)(LB(p, wn >> 1) +                     \
          ((((wn & 1) * 4 + (nh) * 2 + n_) * 2 + ks_) << 10) + lconst)

#define QMFMA(mh, nh)                                                         \
  do {                                                                        \
    BAR;                                                                      \
    LGKM0;                                                                    \
    __builtin_amdgcn_sched_barrier(0);                                        \
    __builtin_amdgcn_s_setprio(1);                                            \
    _Pragma("unroll") for (int mi_ = 0; mi_ < 4; ++mi_)                       \
      _Pragma("unroll") for (int n_ = 0; n_ < 2; ++n_)                        \
        _Pragma("unroll") for (int ks_ = 0; ks_ < 2; ++ks_)                   \
          acc[(mh) * 4 + mi_][(nh) * 2 + n_] =                                \
              __builtin_amdgcn_mfma_f32_16x16x32_bf16(                        \
                  af[mi_][ks_], bf[nh][n_][ks_],                              \
                  acc[(mh) * 4 + mi_][(nh) * 2 + n_], 0, 0, 0);               \
    __builtin_amdgcn_s_setprio(0);                                            \
  } while (0)

__global__ __launch_bounds__(512) void gemm2_8ph2(
    const unsigned short* __restrict__ A,   // dec_bf [8*2048][512]
    const unsigned short* __restrict__ Bt,  // encW   [8*2048][512]
    float* __restrict__ C, const float* __restrict__ bias) {
  __shared__ __align__(16) char Lds[131072];

  const int flat = blockIdx.x;                 // 512 blocks: z pins batch->XCD
  const int z = flat & 7;
  const int work = flat >> 3;
  const int by = work & 7, bx = work >> 3;

  const int tid = threadIdx.x;
  const int w = tid >> 6, lane = tid & 63;
  const int wm = w >> 2, wn = w & 3;           // 2 x 4 waves, 128x64 out each
  const int base_r = lane & 15, q = lane >> 4;
  const int lconst = base_r * 64 + ((q * 16) ^ ((base_r & 8) << 2));
  const int srow = lane >> 2;
  const int scol = ((lane & 3) * 8) ^ (((lane >> 5) & 1) << 4);

  const unsigned short* Ab = A + ((long)z * 2048 + bx * 256) * 512;
  const unsigned short* Bb = Bt + ((long)z * 2048 + by * 256) * 512;

  f32x4 acc[8][4] = {};
  short8 af[4][2];      // current A bank [mi][ks]
  short8 bf[2][2][2];   // [nh][n][ks]

  // prologue: T0 all 4 halves + T1 {B0, A0}
  STGH(Bb, LB(0, 0), 0, 0);
  STGH(Bb, LB(0, 1), 0, 1);
  STGH(Ab, LA(0, 0), 0, 0);
  STGH(Ab, LA(0, 1), 0, 1);
  STGH(Bb, LB(1, 0), 1, 0);
  STGH(Ab, LA(1, 0), 1, 0);
  VMCNT(4);                   // T0 landed; T1 {B0,A0} in flight
  BAR;

  for (int t = 0; t < 3; ++t) {
    const int T1v = 2 * t + 1, T2v = 2 * t + 2, T3v = 2 * t + 3;
    // ph1 (T_even: mh0,nh0) — stage T1v.A1
    LOADAF(0, 0); LOADBF(0, 0);
    STGH(Ab, LA(1, 1), T1v, 1);
    QMFMA(0, 0); BAR;
    // ph2 — stage T1v.B1
    LOADBF(0, 1);
    STGH(Bb, LB(1, 1), T1v, 1);
    QMFMA(0, 1); BAR;
    // ph3 — stage T2v.B0
    LOADAF(0, 1);
    STGH(Bb, LB(0, 0), T2v, 0);
    QMFMA(1, 0); BAR;
    // ph4 — stage T2v.B1; retire all of T1v
    STGH(Bb, LB(0, 1), T2v, 1);
    QMFMA(1, 1); VMCNT(4); BAR;
    // ph5 (T_odd: mh0,nh0) — stage T2v.A0
    LOADAF(1, 0); LOADBF(1, 0);
    STGH(Ab, LA(0, 0), T2v, 0);
    QMFMA(0, 0); BAR;
    // ph6 — stage T2v.A1
    LOADBF(1, 1);
    STGH(Ab, LA(0, 1), T2v, 1);
    QMFMA(0, 1); BAR;
    // ph7 — stage T3v.B0
    LOADAF(1, 1);
    STGH(Bb, LB(1, 0), T3v, 0);
    QMFMA(1, 0); BAR;
    // ph8 — stage T3v.A0; retire all of T2v
    STGH(Ab, LA(1, 0), T3v, 0);
    QMFMA(1, 1); VMCNT(4); BAR;
  }
  // tail: tile 6 in buffer 0 (landed), tile 7 needs A1/B1 staged (THE FIX)
  LOADAF(0, 0); LOADBF(0, 0);
  STGH(Ab, LA(1, 1), 7, 1);                  // T7.A1 (dest last read t=2 ph7)
  QMFMA(0, 0); BAR;
  LOADBF(0, 1);
  STGH(Bb, LB(1, 1), 7, 1);                  // T7.B1 (dest last read t=2 ph6)
  QMFMA(0, 1); BAR;
  LOADAF(0, 1);               QMFMA(1, 0); BAR;
                              QMFMA(1, 1); VMCNT(0); BAR;   // T7 fully landed
  LOADAF(1, 0); LOADBF(1, 0); QMFMA(0, 0); BAR;
  LOADBF(1, 1);               QMFMA(0, 1); BAR;
  LOADAF(1, 1);               QMFMA(1, 0); BAR;
                              QMFMA(1, 1);

  const float bv = bias[0];
  float* Cb = C + ((long)z * 2048 + bx * 256 + wm * 128) * 2048 + by * 256 + wn * 64;
#pragma unroll
  for (int m = 0; m < 8; ++m)
#pragma unroll
    for (int n = 0; n < 4; ++n)
#pragma unroll
      for (int j = 0; j < 4; ++j)
        Cb[(long)(m * 16 + q * 4 + j) * 2048 + n * 16 + base_r] = acc[m][n][j] + bv;
}

extern "C" void kernel_launch(void* const* d_in, const int* in_sizes, int n_in,
                              void* d_out, int out_size, void* d_ws, size_t ws_size,
                              hipStream_t stream) {
  const float* enc  = (const float*)d_in[0];  // [8,2048,512]
  const float* dec  = (const float*)d_in[1];  // [8,2048,512]
  const float* W    = (const float*)d_in[2];  // [1,512,512]
  const float* bias = (const float*)d_in[3];  // [1]
  float* out = (float*)d_out;                 // [8,2048,2048] fp32

  constexpr int Bn = 8, S = 2048, H = 512;
  constexpr long NE = (long)Bn * S * H;       // 8388608

  unsigned short* dec_bf = (unsigned short*)d_ws;        // 16.8 MB
  unsigned short* Wt     = dec_bf + NE;                  // 0.5 MB
  unsigned short* encW   = Wt + (long)H * H;             // 16.8 MB

  wt_kernel<<<dim3(8, 8), 256, 0, stream>>>(W, Wt);

  // gemm1 (512 blocks) + dec conversion (4096 blocks) in one launch
  gemm1_plus_cvtdec<<<dim3(512 + 4096, 1, 1), 256, 0, stream>>>(
      enc, Wt, encW, dec, dec_bf);

  // scores[b][d][e] = dec[b,d,:] . encW[b,e,:] + bias
  gemm2_8ph2<<<dim3(512, 1, 1), 512, 0, stream>>>(dec_bf, encW, out, bias);
}